// Round 1
// baseline (108912.048 us; speedup 1.0000x reference)
//
#include <hip/hip_runtime.h>
#include <hip/hip_cooperative_groups.h>
#include <math.h>

namespace cg = cooperative_groups;

namespace {
constexpr int Bn  = 128;
constexpr int Tn  = 512;
constexpr int Hn  = 1024;
constexpr int H3n = 3072;
constexpr long HH = (long)Hn * Hn;      // elements per gate block of W
constexpr int BHn = Bn * Hn;            // 131072 elements per h-state

__device__ __forceinline__ float sigm(float x) { return 1.0f / (1.0f + expf(-x)); }
}

// Persistent cooperative kernel.
// Grid: 256 blocks x 512 threads. Block tile: 64 batch-rows x 8 hidden-cols.
// Each block's 8 waves split K=1024 into 8 x 128; partials reduced via LDS.
// One grid.sync() per layer-step (2 per timestep).
// ws layout: h1[0], h1[1], h2[0], h2[1] -- each BHn floats (2 MiB total).
extern "C" __global__ void __launch_bounds__(512, 1)
gru_coop(const float* __restrict__ x_in, const float* __restrict__ enc,
         const float* __restrict__ Wih, const float* __restrict__ Whh,
         const float* __restrict__ bih, const float* __restrict__ bhh,
         float* __restrict__ out, float* __restrict__ ws)
{
  __shared__ float red[8][6][64][8];  // 96 KiB: [wave][gate][row][col]
  cg::grid_group grid = cg::this_grid();

  // init both layers' h state (buffer 0) from encoder_h; grid*block == BHn exactly
  {
    const int gt = blockIdx.x * blockDim.x + threadIdx.x;
    if (gt < BHn) {
      const float v = enc[gt];
      ws[gt]           = v;   // h1[0]
      ws[2L*BHn + gt]  = v;   // h2[0]
    }
  }
  grid.sync();

  const int tid   = threadIdx.x;
  const int wv    = tid >> 6;        // wave 0..7 -> K-chunk
  const int lane  = tid & 63;
  const int col   = lane & 7;        // 0..7 within block col tile
  const int rowg  = lane >> 3;       // 0..7 -> 8 batch rows each
  const int mtile = blockIdx.x & 1;
  const int jtile = blockIdx.x >> 1; // 0..127
  const int j     = (jtile << 3) + col;           // hidden col 0..1023
  const int b0    = (mtile << 6) + (rowg << 3);   // first of 8 batch rows
  const int k0    = wv << 7;                      // K offset (8 x 128)
  const int rr    = tid >> 3;        // reduction-phase local row 0..63
  const int cc    = tid & 7;         // reduction-phase col 0..7
  const int jj    = (jtile << 3) + cc;
  const int bb    = (mtile << 6) + rr;

  for (int t = 0; t < Tn; ++t) {
    const int cur = t & 1;
    const int nxt = cur ^ 1;
    float* h1c = ws + (long)cur * BHn;
    float* h1n = ws + (long)nxt * BHn;
    float* h2c = ws + 2L*BHn + (long)cur * BHn;
    float* h2n = ws + 2L*BHn + (long)nxt * BHn;

    #pragma unroll
    for (int l = 0; l < 2; ++l) {
      const float* xb; long xstr; const float* hp; float* hw;
      if (l == 0) { xb = x_in + (long)t * Hn; xstr = (long)Tn * Hn; hp = h1c; hw = h1n; }
      else        { xb = h1n;                 xstr = Hn;            hp = h2c; hw = h2n; }

      const float* wi0 = Wih + (long)l * H3n * Hn + (long)j * Hn + k0;
      const float* wh0 = Whh + (long)l * H3n * Hn + (long)j * Hn + k0;
      const float4* wir = (const float4*)wi0;
      const float4* wiz = (const float4*)(wi0 + HH);
      const float4* win = (const float4*)(wi0 + 2 * HH);
      const float4* whr = (const float4*)wh0;
      const float4* whz = (const float4*)(wh0 + HH);
      const float4* whn = (const float4*)(wh0 + 2 * HH);

      const float4* xr[8]; const float4* hr[8];
      #pragma unroll
      for (int r = 0; r < 8; ++r) {
        xr[r] = (const float4*)(xb + (long)(b0 + r) * xstr + k0);
        hr[r] = (const float4*)(hp + (long)(b0 + r) * Hn + k0);
      }

      float acc[6][8];
      #pragma unroll
      for (int g = 0; g < 6; ++g)
        #pragma unroll
        for (int r = 0; r < 8; ++r) acc[g][r] = 0.0f;

      for (int kk = 0; kk < 32; ++kk) {
        const float4 a0 = wir[kk], a1 = wiz[kk], a2 = win[kk];
        const float4 c0 = whr[kk], c1 = whz[kk], c2 = whn[kk];
        #pragma unroll
        for (int r = 0; r < 8; ++r) {
          const float4 xv = xr[r][kk];
          const float4 hv = hr[r][kk];
          acc[0][r] += xv.x*a0.x + xv.y*a0.y + xv.z*a0.z + xv.w*a0.w;
          acc[1][r] += xv.x*a1.x + xv.y*a1.y + xv.z*a1.z + xv.w*a1.w;
          acc[2][r] += xv.x*a2.x + xv.y*a2.y + xv.z*a2.z + xv.w*a2.w;
          acc[3][r] += hv.x*c0.x + hv.y*c0.y + hv.z*c0.z + hv.w*c0.w;
          acc[4][r] += hv.x*c1.x + hv.y*c1.y + hv.z*c1.z + hv.w*c1.w;
          acc[5][r] += hv.x*c2.x + hv.y*c2.y + hv.z*c2.z + hv.w*c2.w;
        }
      }

      #pragma unroll
      for (int g = 0; g < 6; ++g)
        #pragma unroll
        for (int r = 0; r < 8; ++r)
          red[wv][g][(rowg << 3) + r][col] = acc[g][r];
      __syncthreads();

      {
        float s[6];
        #pragma unroll
        for (int g = 0; g < 6; ++g) {
          float v = 0.0f;
          #pragma unroll
          for (int w = 0; w < 8; ++w) v += red[w][g][rr][cc];
          s[g] = v;
        }
        const float ir  = s[0] + bih[l * H3n + jj];
        const float iz  = s[1] + bih[l * H3n + Hn + jj];
        const float inn = s[2] + bih[l * H3n + 2 * Hn + jj];
        const float hrv = s[3] + bhh[l * H3n + jj];
        const float hzv = s[4] + bhh[l * H3n + Hn + jj];
        const float hnv = s[5] + bhh[l * H3n + 2 * Hn + jj];
        const float rg = sigm(ir + hrv);
        const float zg = sigm(iz + hzv);
        const float ng = tanhf(inn + rg * hnv);
        const float hpv = hp[(long)bb * Hn + jj];
        const float hnew = (1.0f - zg) * ng + zg * hpv;
        hw[(long)bb * Hn + jj] = hnew;
        if (l == 1) {
          out[(long)bb * Tn * Hn + (long)t * Hn + jj] = hnew;
          if (t == Tn - 1) out[(long)Bn * Tn * Hn + (long)bb * Hn + jj] = hnew;
        }
      }
      grid.sync();
    }
  }
}

extern "C" void kernel_launch(void* const* d_in, const int* in_sizes, int n_in,
                              void* d_out, int out_size, void* d_ws, size_t ws_size,
                              hipStream_t stream) {
  const float* x_in = (const float*)d_in[0];
  const float* enc  = (const float*)d_in[1];
  const float* Wih  = (const float*)d_in[2];
  const float* Whh  = (const float*)d_in[3];
  const float* bih  = (const float*)d_in[4];
  const float* bhh  = (const float*)d_in[5];
  float* out = (float*)d_out;
  float* ws  = (float*)d_ws;

  void* args[] = { (void*)&x_in, (void*)&enc, (void*)&Wih, (void*)&Whh,
                   (void*)&bih, (void*)&bhh, (void*)&out, (void*)&ws };
  hipLaunchCooperativeKernel((const void*)gru_coop, dim3(256), dim3(512),
                             args, 0, stream);
}

// Round 2
// 49620.096 us; speedup vs baseline: 2.1949x; 2.1949x over previous
//
#include <hip/hip_runtime.h>
#include <hip/hip_cooperative_groups.h>
#include <math.h>

namespace cg = cooperative_groups;

typedef __attribute__((ext_vector_type(8))) short bf16x8;
typedef __attribute__((ext_vector_type(4))) float f32x4;
typedef __attribute__((ext_vector_type(4))) short short4v;

namespace {
constexpr int Bn = 128, Tn = 512, Hn = 1024, H3 = 3072;
constexpr int BH = Bn * Hn;                 // 131072
constexpr long WEL = (long)2 * H3 * Hn;     // elements in one weight tensor (L*3H*H)
constexpr int NBLK = 256, NTHR = 384;       // 6 waves/block
constexpr long NT = (long)NBLK * NTHR;      // 98304 threads

__device__ __forceinline__ float sigm(float x) { return 1.0f / (1.0f + expf(-x)); }

// fp32 -> bf16 round-to-nearest-even
__device__ __forceinline__ short f2b(float f) {
  union { float f; unsigned u; } v; v.f = f;
  unsigned r = (v.u + 0x7fffu + ((v.u >> 16) & 1u)) >> 16;
  return (short)r;
}
}

// ws layout (element pointers):
//   short wbf[2*WEL]      : Wih_bf16 (WEL) then Whh_bf16 (WEL)   25.2 MB
//   float h0f[2][BH], h1f[2][BH]                                  2.0 MB
//   short h0b[2][BH], h1b[2][BH]                                  1.0 MB
//
// Superphase s (0..512), one grid.sync each:
//   layer-0 blocks (s<512): h0[s] = GRU0(x[s], h0[s-1])
//   layer-1 blocks (s>=1):  h1[s-1] = GRU1(h0[s-1], h1[s-2])
// Parities: h0 write s&1, read (s+1)&1. h1 write (s-1)&1, read s&1.
extern "C" __global__ void __launch_bounds__(NTHR, 1)
gru_mfma(const float* __restrict__ x_in, const float* __restrict__ enc,
         const float* __restrict__ Wih, const float* __restrict__ Whh,
         const float* __restrict__ bih, const float* __restrict__ bhh,
         float* __restrict__ out, float* __restrict__ ws)
{
  __shared__ float red[6][64][17];  // [gate][row64][col16+pad] ~27.7 KB
  cg::grid_group grid = cg::this_grid();

  short* wbf = (short*)ws;
  float* h0f = (float*)(wbf + 2 * WEL);
  float* h1f = h0f + 2 * BH;
  short* h0b = (short*)(h1f + 2 * BH);
  short* h1b = h0b + 2 * BH;

  const long gtid = (long)blockIdx.x * NTHR + threadIdx.x;

  // ---- prologue: convert weights to bf16; init h states (parity 1) ----
  for (long i = gtid; i < (2 * WEL) / 4; i += NT) {
    const long el = i * 4;
    const float* src = (el < WEL) ? (Wih + el) : (Whh + (el - WEL));
    f32x4 v = *(const f32x4*)src;
    short4v o;
    o[0] = f2b(v[0]); o[1] = f2b(v[1]); o[2] = f2b(v[2]); o[3] = f2b(v[3]);
    *(short4v*)(wbf + el) = o;
  }
  for (long i = gtid; i < BH; i += NT) {
    const float v = enc[i];
    h0f[BH + i] = v; h1f[BH + i] = v;
    const short b = f2b(v);
    h0b[BH + i] = b; h1b[BH + i] = b;
  }
  grid.sync();

  // ---- block mapping: keep each XCD's weight slice fixed & L2-resident ----
  const int idx  = blockIdx.x;
  const int xcd  = idx & 7;
  const int slot = idx >> 3;            // 0..31
  const int mt   = slot & 1;            // batch half
  const int ljt  = xcd * 16 + (slot >> 1);  // 0..127
  const int layer = ljt >> 6;
  const int jt    = ljt & 63;           // 16-col j tile

  const int tid  = threadIdx.x;
  const int wv   = tid >> 6;            // 0..5 -> gate matrix
  const int lane = tid & 63;
  const int col  = lane & 15;
  const int kg   = lane >> 4;           // k-group 0..3
  const int g    = (wv < 3) ? wv : wv - 3;
  const bool hside = (wv >= 3);

  // B fragment base: weight row j3 = g*Hn + jt*16 + col, contiguous k
  const short* wside = wbf + (hside ? WEL : 0) + (long)layer * H3 * Hn;
  const short* bptr  = wside + ((long)(g * Hn + jt * 16 + col)) * Hn + kg * 8;

  const float* bi = bih + layer * H3;
  const float* bh = bhh + layer * H3;
  float* out2 = out + (long)Bn * Tn * Hn;

  for (int s = 0; s <= Tn; ++s) {
    const bool active = (layer == 0) ? (s < Tn) : (s >= 1);
    if (active) {
      const int t = (layer == 0) ? s : s - 1;
      // state buffers for this phase
      const float* hpf; float* hwf; short* hwb; const short* hab; const short* xab;
      bool x_is_f32;
      const float* xf = nullptr;
      if (layer == 0) {
        hpf = h0f + ((s + 1) & 1) * BH;         // h0[s-1] fp32
        hwf = h0f + (s & 1) * BH;
        hwb = h0b + (s & 1) * BH;
        hab = h0b + ((s + 1) & 1) * BH;         // A (h side) bf16
        x_is_f32 = true; xf = x_in;             // A (x side) fp32 x[:,t,:]
        xab = nullptr;
      } else {
        hpf = h1f + (s & 1) * BH;               // h1[s-2] fp32
        hwf = h1f + ((s - 1) & 1) * BH;
        hwb = h1b + ((s - 1) & 1) * BH;
        hab = h1b + (s & 1) * BH;
        x_is_f32 = false;
        xab = h0b + ((s - 1) & 1) * BH;         // "x" input = h0[t] bf16
      }

      // A-operand lane pointers for 4 m-tiles (rows b = mt*64 + m*16 + col)
      const short* ab[4]; const float* af[4];
      #pragma unroll
      for (int m = 0; m < 4; ++m) {
        const int brow = mt * 64 + m * 16 + col;
        if (!hside) {
          if (x_is_f32) af[m] = xf + ((long)brow * Tn + t) * Hn + kg * 8;
          else          ab[m] = xab + (long)brow * Hn + kg * 8;
        } else {
          ab[m] = hab + (long)brow * Hn + kg * 8;
        }
      }

      f32x4 acc[4];
      #pragma unroll
      for (int m = 0; m < 4; ++m) acc[m] = (f32x4){0.f, 0.f, 0.f, 0.f};

      const bool fpath = (!hside) && x_is_f32;
      if (fpath) {
        for (int k0 = 0; k0 < Hn; k0 += 32) {
          bf16x8 bfr = *(const bf16x8*)(bptr + k0);
          #pragma unroll
          for (int m = 0; m < 4; ++m) {
            f32x4 lo = *(const f32x4*)(af[m] + k0);
            f32x4 hi = *(const f32x4*)(af[m] + k0 + 4);
            bf16x8 afr;
            afr[0] = f2b(lo[0]); afr[1] = f2b(lo[1]); afr[2] = f2b(lo[2]); afr[3] = f2b(lo[3]);
            afr[4] = f2b(hi[0]); afr[5] = f2b(hi[1]); afr[6] = f2b(hi[2]); afr[7] = f2b(hi[3]);
            acc[m] = __builtin_amdgcn_mfma_f32_16x16x32_bf16(afr, bfr, acc[m], 0, 0, 0);
          }
        }
      } else {
        for (int k0 = 0; k0 < Hn; k0 += 32) {
          bf16x8 bfr = *(const bf16x8*)(bptr + k0);
          #pragma unroll
          for (int m = 0; m < 4; ++m) {
            bf16x8 afr = *(const bf16x8*)(ab[m] + k0);
            acc[m] = __builtin_amdgcn_mfma_f32_16x16x32_bf16(afr, bfr, acc[m], 0, 0, 0);
          }
        }
      }

      // write C frags to LDS: row = m*16 + kg*4 + r, col = lane&15
      #pragma unroll
      for (int m = 0; m < 4; ++m)
        #pragma unroll
        for (int r = 0; r < 4; ++r)
          red[wv][m * 16 + kg * 4 + r][col] = acc[m][r];
      __syncthreads();

      // gate combine: 1024 outputs by threads 0..255, 4 each
      if (tid < 256) {
        #pragma unroll
        for (int e = 0; e < 4; ++e) {
          const int oi  = tid + e * 256;
          const int row = oi >> 4, cx = oi & 15;
          const int b = mt * 64 + row;
          const int j = jt * 16 + cx;
          const float ir  = red[0][row][cx], iz = red[1][row][cx], inn = red[2][row][cx];
          const float hr  = red[3][row][cx], hz = red[4][row][cx], hn  = red[5][row][cx];
          const float rg = sigm(ir + bi[j] + hr + bh[j]);
          const float zg = sigm(iz + bi[Hn + j] + hz + bh[Hn + j]);
          const float ng = tanhf(inn + bi[2 * Hn + j] + rg * (hn + bh[2 * Hn + j]));
          const float hp = hpf[(long)b * Hn + j];
          const float hnew = (1.f - zg) * ng + zg * hp;
          hwf[(long)b * Hn + j] = hnew;
          hwb[(long)b * Hn + j] = f2b(hnew);
          if (layer == 1) {
            out[(long)b * Tn * Hn + (long)t * Hn + j] = hnew;
            if (t == Tn - 1) out2[(long)b * Hn + j] = hnew;
          }
        }
      }
    }
    grid.sync();
  }
}

extern "C" void kernel_launch(void* const* d_in, const int* in_sizes, int n_in,
                              void* d_out, int out_size, void* d_ws, size_t ws_size,
                              hipStream_t stream) {
  const float* x_in = (const float*)d_in[0];
  const float* enc  = (const float*)d_in[1];
  const float* Wih  = (const float*)d_in[2];
  const float* Whh  = (const float*)d_in[3];
  const float* bih  = (const float*)d_in[4];
  const float* bhh  = (const float*)d_in[5];
  float* out = (float*)d_out;
  float* ws  = (float*)d_ws;

  void* args[] = { (void*)&x_in, (void*)&enc, (void*)&Wih, (void*)&Whh,
                   (void*)&bih, (void*)&bhh, (void*)&out, (void*)&ws };
  hipLaunchCooperativeKernel((const void*)gru_mfma, dim3(NBLK), dim3(NTHR),
                             args, 0, stream);
}